// Round 10
// baseline (147.314 us; speedup 1.0000x reference)
//
#include <hip/hip_runtime.h>

typedef _Float16 half_t;
typedef _Float16 half2v __attribute__((ext_vector_type(2)));
typedef _Float16 half8 __attribute__((ext_vector_type(8)));
typedef float f32x4 __attribute__((ext_vector_type(4)));

static_assert(sizeof(half8) == 16, "half8 must be 16B");

__device__ inline half8 make_h8(unsigned long lo, unsigned long hi) {
  union { half8 v; unsigned long u[2]; } x;
  x.u[0] = lo; x.u[1] = hi;
  return x.v;
}

__device__ inline float fast_exp2(float x) {
#if __has_builtin(__builtin_amdgcn_exp2f)
  return __builtin_amdgcn_exp2f(x);
#else
  return exp2f(x);
#endif
}

__device__ inline half2v cvt_pk_f16(float lo, float hi) {
  return __builtin_bit_cast(half2v, __builtin_amdgcn_cvt_pkrtz(lo, hi));
}

__device__ inline void gload_lds16(const void* g, void* l) {
  __builtin_amdgcn_global_load_lds(
      (const __attribute__((address_space(1))) unsigned int*)g,
      (__attribute__((address_space(3))) unsigned int*)l, 16, 0, 0);
}

// Merged prep:
//  z < 8 : x [b][c=512][s=1024] f32 -> xr [b][s][c] f16 (LDS tile transpose)
//  z == 8: 4 weight matrices [512][512] f32 -> f16 (layout preserved)
__global__ void prep_kernel(const float* __restrict__ x,
                            const float* __restrict__ w0, const float* __restrict__ w1,
                            const float* __restrict__ w2, const float* __restrict__ w3,
                            half_t* __restrict__ xr, half_t* __restrict__ wout) {
  if (blockIdx.z < 8) {
    __shared__ float t[32][33];
    const int b = blockIdx.z;
    const int c0 = blockIdx.y * 32;
    const int s0 = blockIdx.x * 32;
    const int tx = threadIdx.x, ty = threadIdx.y;  // 32 x 8
    const float* xp = x + ((size_t)b * 512 + c0) * 1024 + s0;
#pragma unroll
    for (int r = 0; r < 4; r++) {
      const int cl = ty + 8 * r;
      t[cl][tx] = xp[(size_t)cl * 1024 + tx];
    }
    __syncthreads();
    half_t* op = xr + ((size_t)b * 1024 + s0) * 512 + c0;
#pragma unroll
    for (int r = 0; r < 4; r++) {
      const int sl = ty + 8 * r;
      op[(size_t)sl * 512 + tx] = (half_t)t[tx][sl];
    }
  } else {
    const int f = blockIdx.x + 32 * blockIdx.y;       // [0,512)
    const int tid = threadIdx.x + 32 * threadIdx.y;   // [0,256)
    const int base = (f * 256 + tid) * 2;             // float4 index, 2 per thread
#pragma unroll
    for (int r = 0; r < 2; r++) {
      const int i = base + r;                         // [0, 262144)
      const int mz = i >> 16;
      const float* src = (mz == 0) ? w0 : (mz == 1) ? w1 : (mz == 2) ? w2 : w3;
      const float4 v = ((const float4*)src)[i & 65535];
      union { half_t e[4]; unsigned long u; } st;
      st.e[0] = (half_t)v.x; st.e[1] = (half_t)v.y;
      st.e[2] = (half_t)v.z; st.e[3] = (half_t)v.w;
      *(unsigned long*)(wout + (size_t)i * 4) = st.u;
    }
  }
}

// C[m][n] = sum_k A[m][k] * W[n][k] + bias[n].  Tile BM x 128, BK=64, 2x2 waves.
// REP: internal measurement repeat (idempotent; acc re-inited per rep).
// MODE 0 (BM=128, grid 4x64x3): A = xr, W = {Wq,Wk,Wv}[z], out f16 (see r8).
// MODE 1 (BM=64, grid 4x128x1): A = attn_out, W = Wo, out f32 to d_out
template <int MODE, int BM, int REP>
__global__ __launch_bounds__(256, 2) void gemm_kernel(
    const half_t* __restrict__ A, const half_t* __restrict__ Wall,
    const float* __restrict__ b0, const float* __restrict__ b1,
    const float* __restrict__ b2, half_t* __restrict__ qkv,
    float* __restrict__ fout) {
  constexpr int K = 512;
  constexpr int IREP = BM / 32;  // 16-row fragments per wave (m-dim)
  __shared__ alignas(16) half_t lA[BM * 64];
  __shared__ alignas(16) half_t lB[128 * 64];

  // XCD swizzle (dispatch index -> logical work), bijective
  int bx, by, bz;
  {
    const int flat = blockIdx.x + gridDim.x * (blockIdx.y + gridDim.y * blockIdx.z);
    const int xcd = flat & 7;
    const int r = flat >> 3;
    if (MODE == 0) {  // 768 = 8 xcd * (4x * 3z * 8yhi);  r = bx + 4*bz + 12*yhi
      bx = r & 3; bz = (r >> 2) % 3; by = (r / 12) * 8 + xcd;
    } else {          // 512 = 8 xcd * (4x * 16yhi);      r = bx + 4*yhi
      bx = r & 3; bz = 0; by = (r >> 2) * 8 + xcd;
    }
  }

  const int z = bz;
  const half_t* W = Wall + (size_t)z * K * 512;
  const float* bias = (MODE == 1) ? b0 : (z == 0 ? b0 : (z == 1 ? b1 : b2));

  const int tid = threadIdx.x;
  const int lane = tid & 63;
  const int wid = tid >> 6;
  const int wm = wid >> 1, wn = wid & 1;  // 2x2 waves: (BM/2 x 64) each
  const int g = lane >> 4, r16 = lane & 15;
  const int m0 = by * BM, n0 = bx * 128;

#pragma unroll 1
  for (int rep = 0; rep < REP; rep++) {
    f32x4 acc[IREP][4];
#pragma unroll
    for (int i = 0; i < IREP; i++)
#pragma unroll
      for (int j = 0; j < 4; j++) acc[i][j] = (f32x4){0.f, 0.f, 0.f, 0.f};

    for (int k0 = 0; k0 < K; k0 += 64) {
      // stage A[BM][64] and B[128][64] f16 tiles; LDS linear, source pre-swizzled
      // so that LDS[row][kb] = A[row][kb ^ ((row&7)<<4)]  (16B-granular XOR)
#pragma unroll
      for (int t = 0; t < BM / 32; t++) {
        const int o = (t * 256 + tid) * 16;  // byte offset in A tile
        const int row = o >> 7;
        const int kbs = (o & 127) ^ ((row & 7) << 4);
        gload_lds16((const char*)(A + (size_t)(m0 + row) * K + k0) + kbs, (char*)lA + o);
      }
#pragma unroll
      for (int t = 0; t < 4; t++) {
        const int o = (t * 256 + tid) * 16;  // byte offset in B tile
        const int row = o >> 7;
        const int kbs = (o & 127) ^ ((row & 7) << 4);
        gload_lds16((const char*)(W + (size_t)(n0 + row) * K + k0) + kbs, (char*)lB + o);
      }
      __syncthreads();
#pragma unroll
      for (int kk = 0; kk < 2; kk++) {
        half8 af[IREP], bf[4];
#pragma unroll
        for (int i = 0; i < IREP; i++) {
          const int row = wm * (BM / 2) + i * 16 + r16;
          const int sw = (row & 7) << 4;
          const char* p = (const char*)lA + row * 128;
          af[i] = make_h8(*(const unsigned long*)(p + ((kk * 64 + g * 8) ^ sw)),
                          *(const unsigned long*)(p + ((kk * 64 + 32 + g * 8) ^ sw)));
        }
#pragma unroll
        for (int j = 0; j < 4; j++) {
          const int row = wn * 64 + j * 16 + r16;
          const int sw = (row & 7) << 4;
          const char* p = (const char*)lB + row * 128;
          bf[j] = make_h8(*(const unsigned long*)(p + ((kk * 64 + g * 8) ^ sw)),
                          *(const unsigned long*)(p + ((kk * 64 + 32 + g * 8) ^ sw)));
        }
#pragma unroll
        for (int i = 0; i < IREP; i++)
#pragma unroll
          for (int j = 0; j < 4; j++)
            acc[i][j] = __builtin_amdgcn_mfma_f32_16x16x32_f16(af[i], bf[j], acc[i][j], 0, 0, 0);
      }
      __syncthreads();
    }

    half_t* dst = (MODE == 0) ? (qkv + (size_t)z * 4194304) : (half_t*)nullptr;
    const float scale = (MODE == 0 && z == 0) ? 0.18033688011112042f : 1.0f;
#pragma unroll
    for (int i = 0; i < IREP; i++) {
#pragma unroll
      for (int j = 0; j < 4; j++) {
        const int n = n0 + wn * 64 + j * 16 + r16;
        const float bvv = bias[n];
        // base m for this (i,j): rr walks m consecutively (aligned 4)
        const int mb = m0 + wm * (BM / 2) + i * 16 + g * 4;
        if (MODE == 0 && z == 2) {
          // V^T with permuted kv order; 4 consecutive s stay consecutive under p()
          const int bb = mb >> 10, s0v = mb & 1023, hh = n >> 6, d = n & 63;
          const int kvb = s0v & 31;
          const int sp0 = (s0v & ~31) | ((((kvb & 15) >> 2) << 3) + ((kvb >> 4) << 2));
          half_t* dp = dst + (size_t)(bb * 8 + hh) * 65536 + ((size_t)d << 10) + sp0;
          union { half_t e[4]; unsigned long u; } st;
#pragma unroll
          for (int rr = 0; rr < 4; rr++) st.e[rr] = (half_t)(acc[i][j][rr] + bvv);
          *(unsigned long*)dp = st.u;
        } else {
#pragma unroll
          for (int rr = 0; rr < 4; rr++) {
            const int m = mb + rr;
            const float v = (acc[i][j][rr] + bvv) * scale;
            if (MODE == 0) {
              const int bb = m >> 10, s = m & 1023, hh = n >> 6, d = n & 63;
              dst[(((size_t)(bb * 8 + hh) * 1024 + s) << 6) + d] = (half_t)v;
            } else {
              fout[(size_t)m * 512 + n] = v;
            }
          }
        }
      }
    }
  }
}

// ---------------- attention ----------------
// Structure identical to round 9 (KVBLK=128, 4 waves, XCD swizzle, no-max
// exp2 softmax).  REP: internal measurement repeat (idempotent).

__device__ inline half8 lds_frag128(const half_t* l, int row, int cb) {
  const char* p = (const char*)l + row * 128 + (cb ^ ((row & 7) << 4));
  return *(const half8*)p;
}

__device__ inline half8 lds_frag256(const half_t* l, int row, int cb) {
  const char* p = (const char*)l + row * 256 + (cb ^ ((row & 7) << 4));
  return *(const half8*)p;
}

template <int REP>
__global__ __launch_bounds__(256) void attn_kernel(
    const half_t* __restrict__ Q, const half_t* __restrict__ Kh,
    const half_t* __restrict__ V, half_t* __restrict__ O) {
  __shared__ alignas(16) half_t lK[2][128 * 64];
  __shared__ alignas(16) half_t lV[2][64 * 128];

  const int tid = threadIdx.x;
  const int lane = tid & 63;
  const int w = tid >> 6;
  // XCD swizzle (grid (8,64) -> flat [0,512)), bijective
  const int flat = blockIdx.x + (blockIdx.y << 3);
  const int xcd = flat & 7;
  const int tt = flat >> 3;      // [0,64)
  const int qch = tt & 7;        // q-chunk
  const int bh = ((tt >> 3) << 3) | xcd;
  const int b = bh >> 3, h = bh & 7;
  const int g = lane >> 4, r16 = lane & 15;
  const size_t base = (size_t)bh * 65536;  // 1024*64
  const half_t* Qp = Q + base;
  const half_t* Kp = Kh + base;
  const half_t* Vt = V + base;  // [64][1024-permuted]
  const int q0 = qch * 128 + w * 32;

  // Q fragments (B operand), contiguous-k permutation: lane holds q-row r16,
  // k elems kk*32 + g*8 .. +7  (single 16B load each)
  half8 qf[2][2];
#pragma unroll
  for (int qt = 0; qt < 2; qt++) {
    const half_t* qrow = Qp + (size_t)(q0 + qt * 16 + r16) * 64 + g * 8;
    qf[qt][0] = *(const half8*)(qrow);
    qf[qt][1] = *(const half8*)(qrow + 32);
  }

  // ---- staging: K tile rows kv0..kv0+127 (16KB), V^T tile [64][kv0..+127] (16KB)
  auto stage = [&](int kv0, int bufi) {
    half_t* lk = lK[bufi];
    half_t* lv = lV[bufi];
    const char* ksrc = (const char*)(Kp + (size_t)kv0 * 64);
    const char* vsrc = (const char*)Vt + (size_t)kv0 * 2;
#pragma unroll
    for (int i = 0; i < 4; i++) {
      const int o = i * 4096 + tid * 16;                 // [0,16384)
      const int krow = o >> 7;                            // 128B rows
      const int kcs = (o & 127) ^ ((krow & 7) << 4);
      gload_lds16(ksrc + krow * 128 + kcs, (char*)lk + o);
      const int vrow = o >> 8;                            // 256B rows
      const int vcs = (o & 255) ^ ((vrow & 7) << 4);
      gload_lds16(vsrc + vrow * 2048 + vcs, (char*)lv + o);
    }
  };

#pragma unroll 1
  for (int rep = 0; rep < REP; rep++) {
    f32x4 acc[2][4];  // per qt: O^T, 4 d-tiles x (rows g*4+rr), col q=r16
#pragma unroll
    for (int qt = 0; qt < 2; qt++)
#pragma unroll
      for (int i = 0; i < 4; i++) acc[qt][i] = (f32x4){0.f, 0.f, 0.f, 0.f};
    float lsum[2] = {0.f, 0.f};

    stage(0, 0);
    __syncthreads();  // drains vmcnt

    int buf = 0;
    for (int kv0 = 0; kv0 < 1024; kv0 += 128) {
      if (kv0 + 128 < 1024) stage(kv0 + 128, buf ^ 1);
      const half_t* lk = lK[buf];
      const half_t* lv = lV[buf];
#pragma unroll
      for (int sub = 0; sub < 4; sub++) {
        half8 kf0 = lds_frag128(lk, sub * 32 + r16, g * 16);
        half8 kf1 = lds_frag128(lk, sub * 32 + r16, 64 + g * 16);
        half8 kf2 = lds_frag128(lk, sub * 32 + 16 + r16, g * 16);
        half8 kf3 = lds_frag128(lk, sub * 32 + 16 + r16, 64 + g * 16);
        half8 vf[4];
#pragma unroll
        for (int dt = 0; dt < 4; dt++)
          vf[dt] = lds_frag256(lv, dt * 16 + r16, sub * 64 + g * 16);

        // ---- phase 1: QK^T for both q-tiles (8 independent MFMA)
        f32x4 s[2][2];
        __builtin_amdgcn_s_setprio(1);
#pragma unroll
        for (int qt = 0; qt < 2; qt++) {
          s[qt][0] = (f32x4){0.f, 0.f, 0.f, 0.f};
          s[qt][1] = (f32x4){0.f, 0.f, 0.f, 0.f};
          s[qt][0] = __builtin_amdgcn_mfma_f32_16x16x32_f16(kf0, qf[qt][0], s[qt][0], 0, 0, 0);
          s[qt][0] = __builtin_amdgcn_mfma_f32_16x16x32_f16(kf1, qf[qt][1], s[qt][0], 0, 0, 0);
          s[qt][1] = __builtin_amdgcn_mfma_f32_16x16x32_f16(kf2, qf[qt][0], s[qt][1], 0, 0, 0);
          s[qt][1] = __builtin_amdgcn_mfma_f32_16x16x32_f16(kf3, qf[qt][1], s[qt][1], 0, 0, 0);
        }
        __builtin_amdgcn_s_setprio(0);

        // ---- phase 2: softmax numerators for both q-tiles (exp2 domain)
        union { half8 v; half2v h2[4]; } pu[2];
#pragma unroll
        for (int qt = 0; qt < 2; qt++) {
          float p[8];
#pragma unroll
          for (int i = 0; i < 4; i++) {
            p[i] = fast_exp2(s[qt][0][i]);
            p[4 + i] = fast_exp2(s[qt][1][i]);
          }
          lsum[qt] += ((p[0] + p[1]) + (p[2] + p[3])) + ((p[4] + p[5]) + (p[6] + p[7]));
#pragma unroll
          for (int i = 0; i < 4; i++)
            pu[qt].h2[i] = cvt_pk_f16(p[2 * i], p[2 * i + 1]);
        }

        // ---- phase 3: PV for both q-tiles (8 independent MFMA)
        __builtin_amdgcn_s_setprio(1);
#pragma unroll
        for (int qt = 0; qt < 2; qt++)
#pragma unroll
          for (int dt = 0; dt < 4; dt++)
            acc[qt][dt] = __builtin_amdgcn_mfma_f32_16x16x32_f16(vf[dt], pu[qt].v, acc[qt][dt], 0, 0, 0);
        __builtin_amdgcn_s_setprio(0);
      }
      __syncthreads();  // drains vmcnt (next tile staged) + lgkm; protects dbuf reuse
      buf ^= 1;
    }

#pragma unroll
    for (int qt = 0; qt < 2; qt++) {
      float l = lsum[qt];
      l += __shfl_xor(l, 16);
      l += __shfl_xor(l, 32);
      const float inv = 1.f / l;
      half_t* orow = O + ((size_t)b * 1024 + q0 + qt * 16 + r16) * 512 + h * 64;
#pragma unroll
      for (int dt = 0; dt < 4; dt++) {
        union { half_t e[4]; unsigned long u; } st;
#pragma unroll
        for (int rr = 0; rr < 4; rr++) st.e[rr] = (half_t)(acc[qt][dt][rr] * inv);
        *(unsigned long*)(orow + dt * 16 + g * 4) = st.u;
      }
    }
  }
}

extern "C" void kernel_launch(void* const* d_in, const int* in_sizes, int n_in,
                              void* d_out, int out_size, void* d_ws, size_t ws_size,
                              hipStream_t stream) {
  if (ws_size < 44040192u) return;  // need ~42 MB scratch
  const float* x  = (const float*)d_in[0];
  const float* Wq = (const float*)d_in[1];
  const float* bq = (const float*)d_in[2];
  const float* Wk = (const float*)d_in[3];
  const float* bk = (const float*)d_in[4];
  const float* Wv = (const float*)d_in[5];
  const float* bv = (const float*)d_in[6];
  const float* Wo = (const float*)d_in[7];
  const float* bo = (const float*)d_in[8];
  char* ws = (char*)d_ws;
  half_t* xr = (half_t*)(ws + 0);          // 8  MB: xr [8][1024][512] f16
  half_t* W4 = (half_t*)(ws + 8388608);    // 2  MB: Wq,Wk,Wv,Wo f16
  half_t* Qb = (half_t*)(ws + 10485760);   // 24 MB: Q,K [b][h][1024][64], Vt [b][h][64][1024p] f16
  half_t* AO = (half_t*)(ws + 35651584);   // 8  MB: attn out [b][s][512] f16
  float* out = (float*)d_out;

  prep_kernel<<<dim3(32, 16, 9), dim3(32, 8), 0, stream>>>(x, Wq, Wk, Wv, Wo, xr, W4);
  // REP=3 on gemm0 and REP=2 on attn: measurement repeats so these dispatches
  // exceed the ~43us poison-fill floor and surface in the top-5 WITH counters.
  gemm_kernel<0, 128, 3><<<dim3(4, 64, 3), 256, 0, stream>>>(xr, W4, bq, bk, bv, Qb, nullptr);
  attn_kernel<2><<<dim3(8, 64), 256, 0, stream>>>(Qb, Qb + 4194304, Qb + 8388608, AO);
  gemm_kernel<1, 64, 1><<<dim3(4, 128, 1), 256, 0, stream>>>(AO, W4 + 786432, bo, nullptr, nullptr,
                                                             nullptr, out);
}

// Round 11
// 67.997 us; speedup vs baseline: 2.1665x; 2.1665x over previous
//
#include <hip/hip_runtime.h>

typedef _Float16 half_t;
typedef _Float16 half2v __attribute__((ext_vector_type(2)));
typedef _Float16 half8 __attribute__((ext_vector_type(8)));
typedef float f32x4 __attribute__((ext_vector_type(4)));

static_assert(sizeof(half8) == 16, "half8 must be 16B");

__device__ inline float fast_exp2(float x) {
#if __has_builtin(__builtin_amdgcn_exp2f)
  return __builtin_amdgcn_exp2f(x);
#else
  return exp2f(x);
#endif
}

__device__ inline half2v cvt_pk_f16(float lo, float hi) {
  return __builtin_bit_cast(half2v, __builtin_amdgcn_cvt_pkrtz(lo, hi));
}

__device__ inline void gload_lds16(const void* g, void* l) {
  __builtin_amdgcn_global_load_lds(
      (const __attribute__((address_space(1))) unsigned int*)g,
      (__attribute__((address_space(3))) unsigned int*)l, 16, 0, 0);
}

// Merged prep:
//  z < 8 : x [b][c=512][s=1024] f32 -> xr [b][s][c] f16 (LDS tile transpose)
//  z == 8: 4 weight matrices [512][512] f32 -> f16 (layout preserved)
__global__ void prep_kernel(const float* __restrict__ x,
                            const float* __restrict__ w0, const float* __restrict__ w1,
                            const float* __restrict__ w2, const float* __restrict__ w3,
                            half_t* __restrict__ xr, half_t* __restrict__ wout) {
  if (blockIdx.z < 8) {
    __shared__ float t[32][33];
    const int b = blockIdx.z;
    const int c0 = blockIdx.y * 32;
    const int s0 = blockIdx.x * 32;
    const int tx = threadIdx.x, ty = threadIdx.y;  // 32 x 8
    const float* xp = x + ((size_t)b * 512 + c0) * 1024 + s0;
#pragma unroll
    for (int r = 0; r < 4; r++) {
      const int cl = ty + 8 * r;
      t[cl][tx] = xp[(size_t)cl * 1024 + tx];
    }
    __syncthreads();
    half_t* op = xr + ((size_t)b * 1024 + s0) * 512 + c0;
#pragma unroll
    for (int r = 0; r < 4; r++) {
      const int sl = ty + 8 * r;
      op[(size_t)sl * 512 + tx] = (half_t)t[tx][sl];
    }
  } else {
    const int f = blockIdx.x + 32 * blockIdx.y;       // [0,512)
    const int tid = threadIdx.x + 32 * threadIdx.y;   // [0,256)
    const int base = (f * 256 + tid) * 2;             // float4 index, 2 per thread
#pragma unroll
    for (int r = 0; r < 2; r++) {
      const int i = base + r;                         // [0, 262144)
      const int mz = i >> 16;
      const float* src = (mz == 0) ? w0 : (mz == 1) ? w1 : (mz == 2) ? w2 : w3;
      const float4 v = ((const float4*)src)[i & 65535];
      union { half_t e[4]; unsigned long u; } st;
      st.e[0] = (half_t)v.x; st.e[1] = (half_t)v.y;
      st.e[2] = (half_t)v.z; st.e[3] = (half_t)v.w;
      *(unsigned long*)(wout + (size_t)i * 4) = st.u;
    }
  }
}

// C[m][n] = sum_k A[m][k] * W[n][k] + bias[n].  Tile BM x 128, BK=64, 2x2 waves.
// Fragment reads: single ds_read_b128 per fragment, contiguous-k permutation
// k = kk*32 + g*8..+7 (identical for A and B -> contraction invariant);
// conflict-free under the 16B XOR swizzle (2 rows/slot = free 2-way).
// MODE 0 (BM=128, grid 4x64x3): A = xr, W = {Wq,Wk,Wv}[z], out f16:
//   z=0 (Q): scaled by 0.125*log2(e), layout [b][h][s][64]
//   z=1 (K): layout [b][h][s][64]
//   z=2 (V): layout [b][h][64][s'] with s' kv-within-32 permuted:
//            p(kv) = ((kv&15)>>2)*8 + (kv>>4)*4 + (kv&3)  (native MFMA k-order)
// MODE 1 (BM=64, grid 4x128x1): A = attn_out, W = Wo, out f32 to d_out
template <int MODE, int BM>
__global__ __launch_bounds__(256, 2) void gemm_kernel(
    const half_t* __restrict__ A, const half_t* __restrict__ Wall,
    const float* __restrict__ b0, const float* __restrict__ b1,
    const float* __restrict__ b2, half_t* __restrict__ qkv,
    float* __restrict__ fout) {
  constexpr int K = 512;
  constexpr int IREP = BM / 32;  // 16-row fragments per wave (m-dim)
  __shared__ alignas(16) half_t lA[BM * 64];
  __shared__ alignas(16) half_t lB[128 * 64];

  // XCD swizzle (dispatch index -> logical work), bijective
  int bx, by, bz;
  {
    const int flat = blockIdx.x + gridDim.x * (blockIdx.y + gridDim.y * blockIdx.z);
    const int xcd = flat & 7;
    const int r = flat >> 3;
    if (MODE == 0) {  // 768 = 8 xcd * (4x * 3z * 8yhi);  r = bx + 4*bz + 12*yhi
      bx = r & 3; bz = (r >> 2) % 3; by = (r / 12) * 8 + xcd;
    } else {          // 512 = 8 xcd * (4x * 16yhi);      r = bx + 4*yhi
      bx = r & 3; bz = 0; by = (r >> 2) * 8 + xcd;
    }
  }

  const int z = bz;
  const half_t* W = Wall + (size_t)z * K * 512;
  const float* bias = (MODE == 1) ? b0 : (z == 0 ? b0 : (z == 1 ? b1 : b2));

  const int tid = threadIdx.x;
  const int lane = tid & 63;
  const int wid = tid >> 6;
  const int wm = wid >> 1, wn = wid & 1;  // 2x2 waves: (BM/2 x 64) each
  const int g = lane >> 4, r16 = lane & 15;
  const int m0 = by * BM, n0 = bx * 128;

  f32x4 acc[IREP][4];
#pragma unroll
  for (int i = 0; i < IREP; i++)
#pragma unroll
    for (int j = 0; j < 4; j++) acc[i][j] = (f32x4){0.f, 0.f, 0.f, 0.f};

  for (int k0 = 0; k0 < K; k0 += 64) {
    // stage A[BM][64] and B[128][64] f16 tiles; LDS linear, source pre-swizzled
    // so that LDS[row][kb] = A[row][kb ^ ((row&7)<<4)]  (16B-granular XOR)
#pragma unroll
    for (int t = 0; t < BM / 32; t++) {
      const int o = (t * 256 + tid) * 16;  // byte offset in A tile
      const int row = o >> 7;
      const int kbs = (o & 127) ^ ((row & 7) << 4);
      gload_lds16((const char*)(A + (size_t)(m0 + row) * K + k0) + kbs, (char*)lA + o);
    }
#pragma unroll
    for (int t = 0; t < 4; t++) {
      const int o = (t * 256 + tid) * 16;  // byte offset in B tile
      const int row = o >> 7;
      const int kbs = (o & 127) ^ ((row & 7) << 4);
      gload_lds16((const char*)(W + (size_t)(n0 + row) * K + k0) + kbs, (char*)lB + o);
    }
    __syncthreads();
#pragma unroll
    for (int kk = 0; kk < 2; kk++) {
      half8 af[IREP], bf[4];
#pragma unroll
      for (int i = 0; i < IREP; i++) {
        const int row = wm * (BM / 2) + i * 16 + r16;
        const int sw = (row & 7) << 4;
        af[i] = *(const half8*)((const char*)lA + row * 128 + ((kk * 64 + g * 16) ^ sw));
      }
#pragma unroll
      for (int j = 0; j < 4; j++) {
        const int row = wn * 64 + j * 16 + r16;
        const int sw = (row & 7) << 4;
        bf[j] = *(const half8*)((const char*)lB + row * 128 + ((kk * 64 + g * 16) ^ sw));
      }
#pragma unroll
      for (int i = 0; i < IREP; i++)
#pragma unroll
        for (int j = 0; j < 4; j++)
          acc[i][j] = __builtin_amdgcn_mfma_f32_16x16x32_f16(af[i], bf[j], acc[i][j], 0, 0, 0);
    }
    __syncthreads();
  }

  half_t* dst = (MODE == 0) ? (qkv + (size_t)z * 4194304) : (half_t*)nullptr;
  const float scale = (MODE == 0 && z == 0) ? 0.18033688011112042f : 1.0f;
#pragma unroll
  for (int i = 0; i < IREP; i++) {
#pragma unroll
    for (int j = 0; j < 4; j++) {
      const int n = n0 + wn * 64 + j * 16 + r16;
      const float bvv = bias[n];
      // base m for this (i,j): rr walks m consecutively (aligned 4)
      const int mb = m0 + wm * (BM / 2) + i * 16 + g * 4;
      if (MODE == 0 && z == 2) {
        // V^T with permuted kv order; 4 consecutive s stay consecutive under p()
        const int bb = mb >> 10, s0v = mb & 1023, hh = n >> 6, d = n & 63;
        const int kvb = s0v & 31;
        const int sp0 = (s0v & ~31) | ((((kvb & 15) >> 2) << 3) + ((kvb >> 4) << 2));
        half_t* dp = dst + (size_t)(bb * 8 + hh) * 65536 + ((size_t)d << 10) + sp0;
        union { half_t e[4]; unsigned long u; } st;
#pragma unroll
        for (int rr = 0; rr < 4; rr++) st.e[rr] = (half_t)(acc[i][j][rr] + bvv);
        *(unsigned long*)dp = st.u;
      } else {
#pragma unroll
        for (int rr = 0; rr < 4; rr++) {
          const int m = mb + rr;
          const float v = (acc[i][j][rr] + bvv) * scale;
          if (MODE == 0) {
            const int bb = m >> 10, s = m & 1023, hh = n >> 6, d = n & 63;
            dst[(((size_t)(bb * 8 + hh) * 1024 + s) << 6) + d] = (half_t)v;
          } else {
            fout[(size_t)m * 512 + n] = v;
          }
        }
      }
    }
  }
}

// ---------------- attention ----------------
// Block = 4 waves, one bh, 128 q-rows (32 per wave as 2x 16-row tiles).
// XCD swizzle: the 8 q-blocks of each bh share one XCD so K/V (256 KB/head)
// are L2-resident. KVBLK=128: K[128][64] + V^T[64][128] staged in LDS
// (double-buffered, 64 KB, XOR-swizzled) via global_load_lds, shared by all
// 4 waves; 8 barrier iterations total. Swapped QK^T (S^T = K*Q^T) keeps P
// lane-local. QK^T operands use contiguous-k per lane (common permutation);
// PV uses native k-order with V pre-permuted in global memory.
// Q pre-scaled by 0.125*log2e -> softmax in exp2 domain; no online max
// (scores bounded, softmax shift-invariant).
// K layout [bh][s][64]; V layout [bh][64][s-permuted].

__device__ inline half8 lds_frag128(const half_t* l, int row, int cb) {
  const char* p = (const char*)l + row * 128 + (cb ^ ((row & 7) << 4));
  return *(const half8*)p;
}

__device__ inline half8 lds_frag256(const half_t* l, int row, int cb) {
  const char* p = (const char*)l + row * 256 + (cb ^ ((row & 7) << 4));
  return *(const half8*)p;
}

__global__ __launch_bounds__(256) void attn_kernel(
    const half_t* __restrict__ Q, const half_t* __restrict__ Kh,
    const half_t* __restrict__ V, half_t* __restrict__ O) {
  __shared__ alignas(16) half_t lK[2][128 * 64];
  __shared__ alignas(16) half_t lV[2][64 * 128];

  const int tid = threadIdx.x;
  const int lane = tid & 63;
  const int w = tid >> 6;
  // XCD swizzle (grid (8,64) -> flat [0,512)), bijective
  const int flat = blockIdx.x + (blockIdx.y << 3);
  const int xcd = flat & 7;
  const int tt = flat >> 3;      // [0,64)
  const int qch = tt & 7;        // q-chunk
  const int bh = ((tt >> 3) << 3) | xcd;
  const int b = bh >> 3, h = bh & 7;
  const int g = lane >> 4, r16 = lane & 15;
  const size_t base = (size_t)bh * 65536;  // 1024*64
  const half_t* Qp = Q + base;
  const half_t* Kp = Kh + base;
  const half_t* Vt = V + base;  // [64][1024-permuted]
  const int q0 = qch * 128 + w * 32;

  // Q fragments (B operand), contiguous-k permutation: lane holds q-row r16,
  // k elems kk*32 + g*8 .. +7  (single 16B load each)
  half8 qf[2][2];
#pragma unroll
  for (int qt = 0; qt < 2; qt++) {
    const half_t* qrow = Qp + (size_t)(q0 + qt * 16 + r16) * 64 + g * 8;
    qf[qt][0] = *(const half8*)(qrow);
    qf[qt][1] = *(const half8*)(qrow + 32);
  }

  f32x4 acc[2][4];  // per qt: O^T, 4 d-tiles x (rows g*4+rr), col q=r16
#pragma unroll
  for (int qt = 0; qt < 2; qt++)
#pragma unroll
    for (int i = 0; i < 4; i++) acc[qt][i] = (f32x4){0.f, 0.f, 0.f, 0.f};
  float lsum[2] = {0.f, 0.f};

  // ---- staging: K tile rows kv0..kv0+127 (16KB), V^T tile [64][kv0..+127] (16KB)
  auto stage = [&](int kv0, int bufi) {
    half_t* lk = lK[bufi];
    half_t* lv = lV[bufi];
    const char* ksrc = (const char*)(Kp + (size_t)kv0 * 64);
    const char* vsrc = (const char*)Vt + (size_t)kv0 * 2;
#pragma unroll
    for (int i = 0; i < 4; i++) {
      const int o = i * 4096 + tid * 16;                 // [0,16384)
      const int krow = o >> 7;                            // 128B rows
      const int kcs = (o & 127) ^ ((krow & 7) << 4);
      gload_lds16(ksrc + krow * 128 + kcs, (char*)lk + o);
      const int vrow = o >> 8;                            // 256B rows
      const int vcs = (o & 255) ^ ((vrow & 7) << 4);
      gload_lds16(vsrc + vrow * 2048 + vcs, (char*)lv + o);
    }
  };

  stage(0, 0);
  __syncthreads();  // drains vmcnt

  int buf = 0;
  for (int kv0 = 0; kv0 < 1024; kv0 += 128) {
    if (kv0 + 128 < 1024) stage(kv0 + 128, buf ^ 1);
    const half_t* lk = lK[buf];
    const half_t* lv = lV[buf];
#pragma unroll
    for (int sub = 0; sub < 4; sub++) {
      // K fragments (A operand, contiguous-k): rows sub*32 + {r16, 16+r16},
      // bytes kk*64 + g*16 (single b128 each, conflict-free under XOR)
      half8 kf0 = lds_frag128(lk, sub * 32 + r16, g * 16);
      half8 kf1 = lds_frag128(lk, sub * 32 + r16, 64 + g * 16);
      half8 kf2 = lds_frag128(lk, sub * 32 + 16 + r16, g * 16);
      half8 kf3 = lds_frag128(lk, sub * 32 + 16 + r16, 64 + g * 16);
      // V^T fragments (native k-order via global pre-permutation):
      // row d = dt*16+r16, bytes sub*64 + g*16 (single b128)
      half8 vf[4];
#pragma unroll
      for (int dt = 0; dt < 4; dt++)
        vf[dt] = lds_frag256(lv, dt * 16 + r16, sub * 64 + g * 16);

      // ---- phase 1: QK^T for both q-tiles (8 independent MFMA)
      f32x4 s[2][2];
      __builtin_amdgcn_s_setprio(1);
#pragma unroll
      for (int qt = 0; qt < 2; qt++) {
        s[qt][0] = (f32x4){0.f, 0.f, 0.f, 0.f};
        s[qt][1] = (f32x4){0.f, 0.f, 0.f, 0.f};
        s[qt][0] = __builtin_amdgcn_mfma_f32_16x16x32_f16(kf0, qf[qt][0], s[qt][0], 0, 0, 0);
        s[qt][0] = __builtin_amdgcn_mfma_f32_16x16x32_f16(kf1, qf[qt][1], s[qt][0], 0, 0, 0);
        s[qt][1] = __builtin_amdgcn_mfma_f32_16x16x32_f16(kf2, qf[qt][0], s[qt][1], 0, 0, 0);
        s[qt][1] = __builtin_amdgcn_mfma_f32_16x16x32_f16(kf3, qf[qt][1], s[qt][1], 0, 0, 0);
      }
      __builtin_amdgcn_s_setprio(0);

      // ---- phase 2: softmax numerators for both q-tiles (exp2 domain)
      union { half8 v; half2v h2[4]; } pu[2];
#pragma unroll
      for (int qt = 0; qt < 2; qt++) {
        float p[8];
#pragma unroll
        for (int i = 0; i < 4; i++) {
          p[i] = fast_exp2(s[qt][0][i]);
          p[4 + i] = fast_exp2(s[qt][1][i]);
        }
        lsum[qt] += ((p[0] + p[1]) + (p[2] + p[3])) + ((p[4] + p[5]) + (p[6] + p[7]));
#pragma unroll
        for (int i = 0; i < 4; i++)
          pu[qt].h2[i] = cvt_pk_f16(p[2 * i], p[2 * i + 1]);
      }

      // ---- phase 3: PV for both q-tiles (8 independent MFMA)
      __builtin_amdgcn_s_setprio(1);
#pragma unroll
      for (int qt = 0; qt < 2; qt++)
#pragma unroll
        for (int dt = 0; dt < 4; dt++)
          acc[qt][dt] = __builtin_amdgcn_mfma_f32_16x16x32_f16(vf[dt], pu[qt].v, acc[qt][dt], 0, 0, 0);
      __builtin_amdgcn_s_setprio(0);
    }
    __syncthreads();  // drains vmcnt (next tile staged) + lgkm; protects dbuf reuse
    buf ^= 1;
  }

#pragma unroll
  for (int qt = 0; qt < 2; qt++) {
    float l = lsum[qt];
    l += __shfl_xor(l, 16);
    l += __shfl_xor(l, 32);
    const float inv = 1.f / l;
    half_t* orow = O + ((size_t)b * 1024 + q0 + qt * 16 + r16) * 512 + h * 64;
#pragma unroll
    for (int dt = 0; dt < 4; dt++) {
      union { half_t e[4]; unsigned long u; } st;
#pragma unroll
      for (int rr = 0; rr < 4; rr++) st.e[rr] = (half_t)(acc[qt][dt][rr] * inv);
      *(unsigned long*)(orow + dt * 16 + g * 4) = st.u;
    }
  }
}

extern "C" void kernel_launch(void* const* d_in, const int* in_sizes, int n_in,
                              void* d_out, int out_size, void* d_ws, size_t ws_size,
                              hipStream_t stream) {
  if (ws_size < 44040192u) return;  // need ~42 MB scratch
  const float* x  = (const float*)d_in[0];
  const float* Wq = (const float*)d_in[1];
  const float* bq = (const float*)d_in[2];
  const float* Wk = (const float*)d_in[3];
  const float* bk = (const float*)d_in[4];
  const float* Wv = (const float*)d_in[5];
  const float* bv = (const float*)d_in[6];
  const float* Wo = (const float*)d_in[7];
  const float* bo = (const float*)d_in[8];
  char* ws = (char*)d_ws;
  half_t* xr = (half_t*)(ws + 0);          // 8  MB: xr [8][1024][512] f16
  half_t* W4 = (half_t*)(ws + 8388608);    // 2  MB: Wq,Wk,Wv,Wo f16
  half_t* Qb = (half_t*)(ws + 10485760);   // 24 MB: Q,K [b][h][1024][64], Vt [b][h][64][1024p] f16
  half_t* AO = (half_t*)(ws + 35651584);   // 8  MB: attn out [b][s][512] f16
  float* out = (float*)d_out;

  prep_kernel<<<dim3(32, 16, 9), dim3(32, 8), 0, stream>>>(x, Wq, Wk, Wv, Wo, xr, W4);
  gemm_kernel<0, 128><<<dim3(4, 64, 3), 256, 0, stream>>>(xr, W4, bq, bk, bv, Qb, nullptr);
  attn_kernel<<<dim3(8, 64), 256, 0, stream>>>(Qb, Qb + 4194304, Qb + 8388608, AO);
  gemm_kernel<1, 64><<<dim3(4, 128, 1), 256, 0, stream>>>(AO, W4 + 786432, bo, nullptr, nullptr,
                                                          nullptr, out);
}